// Round 1
// 2145.178 us; speedup vs baseline: 4.1463x; 4.1463x over previous
//
#include <hip/hip_runtime.h>

// Submanifold sparse conv block, fixed problem size:
// n = 400000 voxels, C = 64, spatial dims B=2, T=21, H=400, W=400.
// lin[i] = ((b*21+t)*400+y)*400+x, sorted ascending by construction.
//
// Round-1 change vs previous best (8.9 ms):
//  - O(1) neighbor lookup via dense grid table map[6.72M] (26.9 MB, L3-resident)
//    instead of 27 binary searches (~500 dependent L2 loads per voxel).
//  - float4/ushort4 vectorized channel loop.
//  - wave-shuffle LN reduction (no LDS, no __syncthreads).
//  - binary-search path kept as fallback if workspace can't hold the map.

#define SBB_T 21
#define SBB_H 400
#define SBB_W 400
#define SBB_TOTAL (2 * SBB_T * SBB_H * SBB_W)   /* 6,720,000 grid sites */

__global__ void sbb_lin_kernel(const int* idxs, int* lin, int n) {
    int i = blockIdx.x * 256 + threadIdx.x;
    if (i < n) {
        int b = idxs[4 * i];
        int t = idxs[4 * i + 1];
        int y = idxs[4 * i + 2];
        int x = idxs[4 * i + 3];
        lin[i] = ((b * 21 + t) * 400 + y) * 400 + x;
    }
}

__global__ void sbb_map_init(int* map) {
    int i = blockIdx.x * 256 + threadIdx.x;
    if (i < SBB_TOTAL) map[i] = -1;
}

__global__ void sbb_map_set(const int* lin, int* map, int n) {
    int i = blockIdx.x * 256 + threadIdx.x;
    if (i < n) map[lin[i]] = i;
}

// Diagnostic: fill fp32 output with a constant.
__global__ void sbb_fill_kernel(float* p, int nel, float val) {
    int i = blockIdx.x * 256 + threadIdx.x;
    if (i < nel) p[i] = val;
}

__device__ __forceinline__ float sbb_bf2f(unsigned short u) {
    return __uint_as_float(((unsigned)u) << 16);
}

// One wave (64 lanes) per voxel, lane = output channel.
// feats source is fp32 (conv1) or bf16 workspace (conv2), selected by flag.
// Output is fp32 (conv2) or bf16 workspace (conv1), selected by flag.
__global__ void SparseBasicBlock_69965017252009_kernel(
    const float* featsf,            // [n][64] fp32   (used iff feats_bf16 == 0)
    const unsigned short* featsb,   // [n][64] bf16   (used iff feats_bf16 == 1)
    const float* w,                 // [27][64][64] fp32, [k][cin][cout]
    const float* gamma,             // [64] fp32
    const float* beta,              // [64] fp32
    const float* residual,          // [n][64] fp32 (read iff use_residual)
    float* outf,                    // fp32 out (used iff out_bf16 == 0)
    unsigned short* outb,           // bf16 out (used iff out_bf16 == 1)
    const int* lin,                 // [n] sorted linear indices
    const int* idxs,                // [n][4]
    const int* map,                 // [SBB_TOTAL] lin->voxel or -1 (iff use_map)
    int n,
    int use_residual,
    int feats_bf16,
    int out_bf16,
    int use_map)
{
    int tid = threadIdx.x;
    int vox = blockIdx.x * 4 + (tid >> 6);
    if (vox >= n) return;
    int co = tid & 63;

    int t0 = idxs[4 * vox + 1];
    int y0 = idxs[4 * vox + 2];
    int x0 = idxs[4 * vox + 3];
    int mylin = lin[vox];

    float acc = 0.0f;

    #pragma unroll
    for (int dt = -1; dt <= 1; ++dt) {
        int tt = t0 + dt;
        if (tt < 0 || tt >= SBB_T) continue;
        #pragma unroll
        for (int dy = -1; dy <= 1; ++dy) {
            int yy = y0 + dy;
            if (yy < 0 || yy >= SBB_H) continue;
            #pragma unroll
            for (int dx = -1; dx <= 1; ++dx) {
                int xx = x0 + dx;
                if (xx < 0 || xx >= SBB_W) continue;

                int key = mylin + dt * (SBB_H * SBB_W) + dy * SBB_W + dx;
                int lo;
                if (use_map) {
                    lo = map[key];                 // O(1) lookup, -1 if empty
                } else {
                    int l = 0, h = n;              // fallback: binary search
                    while (l < h) {
                        int m = (l + h) >> 1;
                        if (lin[m] < key) l = m + 1; else h = m;
                    }
                    lo = (l < n && lin[l] == key) ? l : -1;
                }
                if (lo < 0) continue;

                int kk = (dt + 1) * 9 + (dy + 1) * 3 + (dx + 1);
                const float* wr = w + kk * 4096 + co;
                if (feats_bf16) {
                    const unsigned short* fr = featsb + (size_t)lo * 64;
                    #pragma unroll 4
                    for (int c4 = 0; c4 < 16; ++c4) {
                        ushort4 fv = *(const ushort4*)(fr + c4 * 4);
                        const float* wp = wr + c4 * 256;
                        acc += sbb_bf2f(fv.x) * wp[0];
                        acc += sbb_bf2f(fv.y) * wp[64];
                        acc += sbb_bf2f(fv.z) * wp[128];
                        acc += sbb_bf2f(fv.w) * wp[192];
                    }
                } else {
                    const float4* fr = (const float4*)(featsf + (size_t)lo * 64);
                    #pragma unroll 4
                    for (int c4 = 0; c4 < 16; ++c4) {
                        float4 fv = fr[c4];
                        const float* wp = wr + c4 * 256;
                        acc += fv.x * wp[0];
                        acc += fv.y * wp[64];
                        acc += fv.z * wp[128];
                        acc += fv.w * wp[192];
                    }
                }
            }
        }
    }

    // LayerNorm over the 64 lanes of this wave: butterfly shuffle reduce.
    float s = acc, q = acc * acc;
    #pragma unroll
    for (int m = 32; m > 0; m >>= 1) {
        s += __shfl_xor(s, m, 64);
        q += __shfl_xor(q, m, 64);
    }
    float mean = s * 0.015625f;
    float var = q * 0.015625f - mean * mean;
    if (var < 0.0f) var = 0.0f;
    float rstd = rsqrtf(var + 1e-5f);

    float yv = (acc - mean) * rstd * gamma[co] + beta[co];
    int oi = vox * 64 + co;
    if (use_residual) yv += residual[oi];
    if (yv < 0.0f) yv = 0.0f;
    if (out_bf16) {
        unsigned u = __float_as_uint(yv);
        unsigned r = u + 0x7fffu + ((u >> 16) & 1u);
        outb[oi] = (unsigned short)(r >> 16);
    } else {
        outf[oi] = yv;
    }
}

extern "C" void kernel_launch(void* const* d_in, const int* in_sizes, int n_in,
                              void* d_out, int out_size, void* d_ws, size_t ws_size,
                              hipStream_t stream) {
    const float* feats = (const float*)d_in[0];
    const int* idxs = (const int*)d_in[1];
    const float* w1 = (const float*)d_in[2];
    const float* g1 = (const float*)d_in[3];
    const float* b1 = (const float*)d_in[4];
    const float* w2 = (const float*)d_in[5];
    const float* g2 = (const float*)d_in[6];
    const float* b2 = (const float*)d_in[7];
    float* out = (float*)d_out;

    int n = 400000;

    size_t lin_b = (size_t)n * 4;                 // 1.6 MB
    size_t map_b = (size_t)SBB_TOTAL * 4;         // 26.88 MB
    size_t mid_b = (size_t)n * 128;               // 51.2 MB (bf16 [n][64])
    size_t need_min  = lin_b + mid_b;             // 52.8 MB (proven to fit)
    size_t need_full = lin_b + map_b + mid_b;     // 79.7 MB

    if (ws_size < need_min) {
        sbb_fill_kernel<<<(n * 64 + 255) / 256, 256, 0, stream>>>(out, n * 64, 1000.0f);
        return;
    }

    int* lin = (int*)d_ws;
    int use_map = (ws_size >= need_full) ? 1 : 0;
    int* map = nullptr;
    unsigned short* mid;
    if (use_map) {
        map = (int*)((char*)d_ws + lin_b);
        mid = (unsigned short*)((char*)d_ws + lin_b + map_b);
    } else {
        mid = (unsigned short*)((char*)d_ws + lin_b);
    }

    sbb_lin_kernel<<<(n + 255) / 256, 256, 0, stream>>>(idxs, lin, n);
    if (use_map) {
        sbb_map_init<<<(SBB_TOTAL + 255) / 256, 256, 0, stream>>>(map);
        sbb_map_set<<<(n + 255) / 256, 256, 0, stream>>>(lin, map, n);
    }

    // conv1: fp32 feats in, bf16 mid out, no residual
    SparseBasicBlock_69965017252009_kernel<<<n / 4, 256, 0, stream>>>(
        feats, (const unsigned short*)feats, w1, g1, b1, feats,
        (float*)mid, mid, lin, idxs, map, n, 0, 0, 1, use_map);

    // conv2: bf16 mid in, fp32 out, residual = feats
    SparseBasicBlock_69965017252009_kernel<<<n / 4, 256, 0, stream>>>(
        feats, mid, w2, g2, b2, feats,
        out, (unsigned short*)out, lin, idxs, map, n, 1, 1, 0, use_map);
}